// Round 5
// baseline (153.152 us; speedup 1.0000x reference)
//
#include <hip/hip_runtime.h>
#include <math.h>

#define EMBED   768
#define T_DIM   512
#define F_DIM   128
#define TOTAL_PATCH 32768   // 128 batches * 32*8 patches
#define EPS_LN  1e-5f

#define MAGIC_A 0x1327A9E5u
#define MAGIC_B 0x6B1C3D47u

typedef float f32x4_t __attribute__((ext_vector_type(4)));

// cos/sin(2*pi*k/16) — constexpr so fully-unrolled constant indices fold to immediates
__device__ constexpr float CT16[16] = {
  1.0f, 0.92387953251128674f, 0.70710678118654757f, 0.38268343236508984f,
  0.0f, -0.38268343236508984f, -0.70710678118654757f, -0.92387953251128674f,
  -1.0f, -0.92387953251128674f, -0.70710678118654757f, -0.38268343236508984f,
  0.0f, 0.38268343236508984f, 0.70710678118654757f, 0.92387953251128674f
};
__device__ constexpr float ST16[16] = {
  0.0f, 0.38268343236508984f, 0.70710678118654757f, 0.92387953251128674f,
  1.0f, 0.92387953251128674f, 0.70710678118654757f, 0.38268343236508984f,
  0.0f, -0.38268343236508984f, -0.70710678118654757f, -0.92387953251128674f,
  -1.0f, -0.92387953251128674f, -0.70710678118654757f, -0.38268343236508984f
};

// ws float layout:
//   [0..767]       c0 = (Wsum-meanW)*gamma
//   [768..1535]    c1 = (b-meanb)*gamma
//   [1536..1538]   A, B, C
//   [1600..1663]   sync flags (2 x 32 u32, double-magic vs poison)
//   [2048..26623]  32 x 768 partial column sums of W

// ---- fused prep (single launch): 32 blocks stream W in parallel (keeps the
// 4-5-deep load chains that made the 32-block partial fast; the Round-3
// single-block version serialized this on one CU and cost +7.7 µs). Block 31
// is the tail: spin-waits on device-scope flags, then computes layernorm
// constants. All 32 blocks are co-resident on 256 CUs → no dispatch-order
// dependence. Flag init from poison: both magics must match; if ws was NOT
// re-poisoned (stale MAGIC), the stale partials are still byte-correct since
// W is iteration-invariant.
__global__ __launch_bounds__(768) void fpe_prep(const float* __restrict__ W,
                                                const float* __restrict__ b,
                                                const float* __restrict__ gamma,
                                                float* __restrict__ cc) {
  int e = threadIdx.x;
  int g = blockIdx.x;           // 0..31
  int wv = e >> 6, lane = e & 63;

  // partial column sums: rows g, g+32, g+64, g+96, (g=0: +128)
  float s = 0.0f;
  for (int r = g; r < 129; r += 32) s += W[(size_t)r * EMBED + e];
  cc[2048 + g * 768 + e] = s;

  // release: make partials visible device-wide, then set my flags
  __threadfence();
  unsigned* flags = (unsigned*)(cc + 1600);
  if (e == 0) {
    atomicExch(&flags[g],      MAGIC_A);
    atomicExch(&flags[32 + g], MAGIC_B);
  }
  if (g != 31) return;

  // ---- tail block: wait for all partials ----
  if (e < 32) {
    while (atomicAdd(&flags[e], 0u)      != MAGIC_A) {}
    while (atomicAdd(&flags[32 + e], 0u) != MAGIC_B) {}
  }
  __syncthreads();
  __threadfence();   // acquire: invalidate caches before reading partials

  __shared__ float red[12];

  // 32 partials per column; 4 independent chains, L2/IF-hot
  float s0 = 0.0f, s1 = 0.0f, s2 = 0.0f, s3 = 0.0f;
  #pragma unroll
  for (int q = 0; q < 32; q += 4) {
    s0 += cc[2048 + (q + 0) * 768 + e];
    s1 += cc[2048 + (q + 1) * 768 + e];
    s2 += cc[2048 + (q + 2) * 768 + e];
    s3 += cc[2048 + (q + 3) * 768 + e];
  }
  float wsum_e = (s0 + s1) + (s2 + s3);
  float b_e = b[e];

  auto blockSum = [&](float v) -> float {
    for (int m = 1; m <= 32; m <<= 1) v += __shfl_xor(v, m, 64);
    if (lane == 0) red[wv] = v;
    __syncthreads();
    float rr = 0.0f;
    #pragma unroll
    for (int k = 0; k < 12; ++k) rr += red[k];
    __syncthreads();
    return rr;
  };

  float meanW = blockSum(wsum_e) * (1.0f / EMBED);
  float meanb = blockSum(b_e)    * (1.0f / EMBED);
  float u = wsum_e - meanW;
  float v = b_e - meanb;
  float A = blockSum(u * u) * (1.0f / EMBED);
  float B = blockSum(u * v) * (1.0f / EMBED);
  float C = blockSum(v * v) * (1.0f / EMBED);

  float gm = gamma[e];
  cc[e]        = u * gm;
  cc[768 + e]  = v * gm;
  if (e == 0) { cc[1536] = A; cc[1537] = B; cc[1538] = C; }
}

// ---- main: 4 patches per wave; lane = (pp, s); registers only, zero LDS ----
// __launch_bounds__(256, 4): cap VGPR at 128 → 4 waves/SIMD (16 waves/CU).
// Measured decomposition says this kernel is ≈21 µs ≈ its 134-MB memory floor.
__global__ __launch_bounds__(256, 4) void fpe_main(const float* __restrict__ x,
                                                   const float* __restrict__ cc,
                                                   const float* __restrict__ beta,
                                                   float* __restrict__ out) {
  int tid  = threadIdx.x;
  int s    = tid & 15;                      // row within patch / FFT lane
  int lane = tid & 63;
  int p    = blockIdx.x * 16 + (tid >> 4);  // this lane-group's patch id
  int b    = p >> 8;
  int i    = (p >> 3) & 31;
  int j    = p & 7;

  // load my row (16 floats) straight into registers; cached loads — the 4
  // dwordx4 share 128B lines across q0..q3 and neighbor groups (L1 reuse).
  const float* rowp = x + ((size_t)(b * T_DIM + i * 16 + s)) * F_DIM + j * 16;
  float4 q0 = *(const float4*)(rowp + 0);
  float4 q1 = *(const float4*)(rowp + 4);
  float4 q2 = *(const float4*)(rowp + 8);
  float4 q3 = *(const float4*)(rowp + 12);
  float r[16] = { q0.x,q0.y,q0.z,q0.w, q1.x,q1.y,q1.z,q1.w,
                  q2.x,q2.y,q2.z,q2.w, q3.x,q3.y,q3.z,q3.w };

  // even/odd pairing for the real row DFT
  float r0v = r[0], r8v = r[8];
  float ap[8], am[8];
  #pragma unroll
  for (int t = 1; t <= 7; ++t) { ap[t] = r[t] + r[16 - t]; am[t] = r[t] - r[16 - t]; }

  // stage 1: rfft over t, all twiddles are compile-time constants
  float zr[9], zi[9];
  #pragma unroll
  for (int v = 0; v < 9; ++v) {
    float accr = fmaf(CT16[(8 * v) & 15], r8v, r0v);   // r0 + (-1)^v * r8
    float acci = 0.0f;
    #pragma unroll
    for (int t = 1; t <= 7; ++t) {
      accr = fmaf(ap[t], CT16[(v * t) & 15], accr);
      acci = fmaf(am[t], ST16[(v * t) & 15], acci);
    }
    zr[v] = accr;
    zi[v] = -acci;
  }

  // per-lane DIF FFT twiddles (once per kernel)
  float sg8 = (s & 8) ? -1.f : 1.f;
  float sg4 = (s & 4) ? -1.f : 1.f;
  float sg2 = (s & 2) ? -1.f : 1.f;
  float sg1 = (s & 1) ? -1.f : 1.f;
  float a0 = (s & 8) ? -0.39269908169872414f * (float)(s & 7) : 0.0f;   // W16^j
  float a1 = (s & 4) ? -0.78539816339744831f * (float)(s & 3) : 0.0f;   // W8^j
  float c0t = __cosf(a0), d0t = __sinf(a0);
  float c1t = __cosf(a1), d1t = __sinf(a1);
  float c2t = ((s & 3) == 3) ? 0.0f : 1.0f;                             // W4^j: 1 or -i
  float d2t = ((s & 3) == 3) ? -1.0f : 0.0f;

  // stage 2: 16-point complex FFT over s via shuffle butterflies (output order
  // is bit-reversed — irrelevant, we only sum over all bins)
  // log1p terms accumulate as PRODUCTS (2 ILP chains) — one __logf at the end.
  float prod0 = 1.0f, prod1 = 1.0f;
  #pragma unroll
  for (int v = 0; v < 9; ++v) {
    float yr = zr[v], yi = zi[v];
    float tr, ti, ur, ui;
    // span 8
    tr = __shfl_xor(yr, 8, 64); ti = __shfl_xor(yi, 8, 64);
    ur = fmaf(sg8, yr, tr); ui = fmaf(sg8, yi, ti);
    yr = fmaf(ur, c0t, -(ui * d0t)); yi = fmaf(ur, d0t, ui * c0t);
    // span 4
    tr = __shfl_xor(yr, 4, 64); ti = __shfl_xor(yi, 4, 64);
    ur = fmaf(sg4, yr, tr); ui = fmaf(sg4, yi, ti);
    yr = fmaf(ur, c1t, -(ui * d1t)); yi = fmaf(ur, d1t, ui * c1t);
    // span 2
    tr = __shfl_xor(yr, 2, 64); ti = __shfl_xor(yi, 2, 64);
    ur = fmaf(sg2, yr, tr); ui = fmaf(sg2, yi, ti);
    yr = fmaf(ur, c2t, -(ui * d2t)); yi = fmaf(ur, d2t, ui * c2t);
    // span 1, twiddle = 1
    tr = __shfl_xor(yr, 1, 64); ti = __shfl_xor(yi, 1, 64);
    yr = fmaf(sg1, yr, tr); yi = fmaf(sg1, yi, ti);

    float qq = fmaf(yr, yr, yi * yi);
    float term = fmaf(__fsqrt_rn(qq), 0.0625f, 1.0f);   // 1 + |X|/16
    if (v & 1) prod1 *= term; else prod0 *= term;
  }
  float lsum = __logf(prod0 * prod1);

  // reduce over the 16 lanes of this patch group (xor<16 stays in-group)
  lsum += __shfl_xor(lsum, 1, 64);
  lsum += __shfl_xor(lsum, 2, 64);
  lsum += __shfl_xor(lsum, 4, 64);
  lsum += __shfl_xor(lsum, 8, 64);
  float mval = lsum * (1.0f / 144.0f);

  // ---- epilogue: coefficient vectors cached once, full-wave 1KiB stores ----
  const float* sc = cc + 1536;
  float A = sc[0], Bc = sc[1], Cc = sc[2];

  float4 a0v[3], a1v[3], btv[3];
  #pragma unroll
  for (int c = 0; c < 3; ++c) {
    int e = c * 256 + lane * 4;
    a0v[c] = *(const float4*)(cc + e);
    a1v[c] = *(const float4*)(cc + 768 + e);
    btv[c] = *(const float4*)(beta + e);
  }

  int pbase = blockIdx.x * 16 + (tid >> 6) * 4;   // first patch of this wave
  #pragma unroll
  for (int g = 0; g < 4; ++g) {
    float mg   = __shfl(mval, g * 16, 64);        // group g's mean (uniform in group)
    float invg = __frsqrt_rn(fmaf(mg, fmaf(mg, A, 2.0f * Bc), Cc) + EPS_LN);
    size_t ob  = (size_t)(pbase + g) * EMBED + lane * 4;
    #pragma unroll
    for (int c = 0; c < 3; ++c) {
      f32x4_t o;
      o.x = fmaf(fmaf(mg, a0v[c].x, a1v[c].x), invg, btv[c].x);
      o.y = fmaf(fmaf(mg, a0v[c].y, a1v[c].y), invg, btv[c].y);
      o.z = fmaf(fmaf(mg, a0v[c].z, a1v[c].z), invg, btv[c].z);
      o.w = fmaf(fmaf(mg, a0v[c].w, a1v[c].w), invg, btv[c].w);
      // out is write-once, never re-read: nontemporal store keeps L2 clean
      __builtin_nontemporal_store(o, (f32x4_t*)(out + ob + c * 256));
    }
  }
}

extern "C" void kernel_launch(void* const* d_in, const int* in_sizes, int n_in,
                              void* d_out, int out_size, void* d_ws, size_t ws_size,
                              hipStream_t stream) {
  const float* x     = (const float*)d_in[0];
  const float* W     = (const float*)d_in[1];
  const float* b     = (const float*)d_in[2];
  const float* gamma = (const float*)d_in[3];
  const float* beta  = (const float*)d_in[4];
  float* out = (float*)d_out;
  float* cc  = (float*)d_ws;

  fpe_prep<<<32, 768, 0, stream>>>(W, b, gamma, cc);
  fpe_main<<<TOTAL_PATCH / 16, 256, 0, stream>>>(x, cc, beta, out);
}

// Round 6
// 145.895 us; speedup vs baseline: 1.0497x; 1.0497x over previous
//
#include <hip/hip_runtime.h>
#include <math.h>

#define EMBED   768
#define T_DIM   512
#define F_DIM   128
#define TOTAL_PATCH 32768   // 128 batches * 32*8 patches
#define EPS_LN  1e-5f

typedef float f32x4_t __attribute__((ext_vector_type(4)));

// cos/sin(2*pi*k/16) — constexpr so fully-unrolled constant indices fold to immediates
__device__ constexpr float CT16[16] = {
  1.0f, 0.92387953251128674f, 0.70710678118654757f, 0.38268343236508984f,
  0.0f, -0.38268343236508984f, -0.70710678118654757f, -0.92387953251128674f,
  -1.0f, -0.92387953251128674f, -0.70710678118654757f, -0.38268343236508984f,
  0.0f, 0.38268343236508984f, 0.70710678118654757f, 0.92387953251128674f
};
__device__ constexpr float ST16[16] = {
  0.0f, 0.38268343236508984f, 0.70710678118654757f, 0.92387953251128674f,
  1.0f, 0.92387953251128674f, 0.70710678118654757f, 0.38268343236508984f,
  0.0f, -0.38268343236508984f, -0.70710678118654757f, -0.92387953251128674f,
  -1.0f, -0.92387953251128674f, -0.70710678118654757f, -0.38268343236508984f
};

// ws float layout:
//   [0..767]       c0 = (Wsum-meanW)*gamma
//   [768..1535]    c1 = (b-meanb)*gamma
//   [1536..1538]   A, B, C
//   [2048..26623]  32 x 768 partial column sums of W

// ---- prep 1: partial column sums of W (129 x 768), 32 blocks.
// Each block owns 4-5 rows → dependent-load chain of 4-5. Measured best.
// (R3 single-block fusion: +7.7 µs serialization. R5 spin-wait fusion:
// +2-6 µs — tail waits on slowest writer + device-scope fences. Two
// launches with a tiny stats kernel is the cheapest structure tried.)
__global__ __launch_bounds__(768) void fpe_partial(const float* __restrict__ W,
                                                   float* __restrict__ cc) {
  int e = threadIdx.x;
  int g = blockIdx.x;           // 0..31
  float s = 0.0f;
  for (int r = g; r < 129; r += 32) s += W[(size_t)r * EMBED + e];
  cc[2048 + g * 768 + e] = s;
}

// ---- prep 2: reduce partials + layernorm constants (1 block, tiny, L2-hot) ----
__global__ __launch_bounds__(768) void fpe_stats(const float* __restrict__ b,
                                                 const float* __restrict__ gamma,
                                                 float* __restrict__ cc) {
  __shared__ float red[12];
  int e = threadIdx.x;
  int wv = e >> 6, lane = e & 63;

  // 32 partials per column; 4 independent chains, all L2-hot
  float s0 = 0.0f, s1 = 0.0f, s2 = 0.0f, s3 = 0.0f;
  #pragma unroll
  for (int g = 0; g < 32; g += 4) {
    s0 += cc[2048 + (g + 0) * 768 + e];
    s1 += cc[2048 + (g + 1) * 768 + e];
    s2 += cc[2048 + (g + 2) * 768 + e];
    s3 += cc[2048 + (g + 3) * 768 + e];
  }
  float wsum_e = (s0 + s1) + (s2 + s3);
  float b_e = b[e];

  auto blockSum = [&](float v) -> float {
    for (int m = 1; m <= 32; m <<= 1) v += __shfl_xor(v, m, 64);
    if (lane == 0) red[wv] = v;
    __syncthreads();
    float rr = 0.0f;
    #pragma unroll
    for (int k = 0; k < 12; ++k) rr += red[k];
    __syncthreads();
    return rr;
  };

  float meanW = blockSum(wsum_e) * (1.0f / EMBED);
  float meanb = blockSum(b_e)    * (1.0f / EMBED);
  float u = wsum_e - meanW;
  float v = b_e - meanb;
  float A = blockSum(u * u) * (1.0f / EMBED);
  float B = blockSum(u * v) * (1.0f / EMBED);
  float C = blockSum(v * v) * (1.0f / EMBED);

  float g = gamma[e];
  cc[e]        = u * g;
  cc[768 + e]  = v * g;
  if (e == 0) { cc[1536] = A; cc[1537] = B; cc[1538] = C; }
}

// ---- main: 4 patches per wave; lane = (pp, s); registers only, zero LDS ----
// __launch_bounds__(256, 4): cap VGPR at 128 → 4 waves/SIMD (16 waves/CU).
// Measured decomposition: ≈21 µs ≈ its 134-MB memory floor (33.5 MB x-read +
// 100.7 MB out-write @ 6.6 TB/s = 20.4 µs).
__global__ __launch_bounds__(256, 4) void fpe_main(const float* __restrict__ x,
                                                   const float* __restrict__ cc,
                                                   const float* __restrict__ beta,
                                                   float* __restrict__ out) {
  int tid  = threadIdx.x;
  int s    = tid & 15;                      // row within patch / FFT lane
  int lane = tid & 63;
  int p    = blockIdx.x * 16 + (tid >> 4);  // this lane-group's patch id
  int b    = p >> 8;
  int i    = (p >> 3) & 31;
  int j    = p & 7;

  // load my row (16 floats) straight into registers; cached loads — the 4
  // dwordx4 share 128B lines across q0..q3 and neighbor groups (L1 reuse).
  const float* rowp = x + ((size_t)(b * T_DIM + i * 16 + s)) * F_DIM + j * 16;
  float4 q0 = *(const float4*)(rowp + 0);
  float4 q1 = *(const float4*)(rowp + 4);
  float4 q2 = *(const float4*)(rowp + 8);
  float4 q3 = *(const float4*)(rowp + 12);
  float r[16] = { q0.x,q0.y,q0.z,q0.w, q1.x,q1.y,q1.z,q1.w,
                  q2.x,q2.y,q2.z,q2.w, q3.x,q3.y,q3.z,q3.w };

  // even/odd pairing for the real row DFT
  float r0v = r[0], r8v = r[8];
  float ap[8], am[8];
  #pragma unroll
  for (int t = 1; t <= 7; ++t) { ap[t] = r[t] + r[16 - t]; am[t] = r[t] - r[16 - t]; }

  // stage 1: rfft over t, all twiddles are compile-time constants
  float zr[9], zi[9];
  #pragma unroll
  for (int v = 0; v < 9; ++v) {
    float accr = fmaf(CT16[(8 * v) & 15], r8v, r0v);   // r0 + (-1)^v * r8
    float acci = 0.0f;
    #pragma unroll
    for (int t = 1; t <= 7; ++t) {
      accr = fmaf(ap[t], CT16[(v * t) & 15], accr);
      acci = fmaf(am[t], ST16[(v * t) & 15], acci);
    }
    zr[v] = accr;
    zi[v] = -acci;
  }

  // per-lane DIF FFT twiddles (once per kernel)
  float sg8 = (s & 8) ? -1.f : 1.f;
  float sg4 = (s & 4) ? -1.f : 1.f;
  float sg2 = (s & 2) ? -1.f : 1.f;
  float sg1 = (s & 1) ? -1.f : 1.f;
  float a0 = (s & 8) ? -0.39269908169872414f * (float)(s & 7) : 0.0f;   // W16^j
  float a1 = (s & 4) ? -0.78539816339744831f * (float)(s & 3) : 0.0f;   // W8^j
  float c0t = __cosf(a0), d0t = __sinf(a0);
  float c1t = __cosf(a1), d1t = __sinf(a1);
  float c2t = ((s & 3) == 3) ? 0.0f : 1.0f;                             // W4^j: 1 or -i
  float d2t = ((s & 3) == 3) ? -1.0f : 0.0f;

  // stage 2: 16-point complex FFT over s via shuffle butterflies (output order
  // is bit-reversed — irrelevant, we only sum over all bins)
  // log1p terms accumulate as PRODUCTS (2 ILP chains) — one __logf at the end.
  float prod0 = 1.0f, prod1 = 1.0f;
  #pragma unroll
  for (int v = 0; v < 9; ++v) {
    float yr = zr[v], yi = zi[v];
    float tr, ti, ur, ui;
    // span 8
    tr = __shfl_xor(yr, 8, 64); ti = __shfl_xor(yi, 8, 64);
    ur = fmaf(sg8, yr, tr); ui = fmaf(sg8, yi, ti);
    yr = fmaf(ur, c0t, -(ui * d0t)); yi = fmaf(ur, d0t, ui * c0t);
    // span 4
    tr = __shfl_xor(yr, 4, 64); ti = __shfl_xor(yi, 4, 64);
    ur = fmaf(sg4, yr, tr); ui = fmaf(sg4, yi, ti);
    yr = fmaf(ur, c1t, -(ui * d1t)); yi = fmaf(ur, d1t, ui * c1t);
    // span 2
    tr = __shfl_xor(yr, 2, 64); ti = __shfl_xor(yi, 2, 64);
    ur = fmaf(sg2, yr, tr); ui = fmaf(sg2, yi, ti);
    yr = fmaf(ur, c2t, -(ui * d2t)); yi = fmaf(ur, d2t, ui * c2t);
    // span 1, twiddle = 1
    tr = __shfl_xor(yr, 1, 64); ti = __shfl_xor(yi, 1, 64);
    yr = fmaf(sg1, yr, tr); yi = fmaf(sg1, yi, ti);

    float qq = fmaf(yr, yr, yi * yi);
    float term = fmaf(__fsqrt_rn(qq), 0.0625f, 1.0f);   // 1 + |X|/16
    if (v & 1) prod1 *= term; else prod0 *= term;
  }
  float lsum = __logf(prod0 * prod1);

  // reduce over the 16 lanes of this patch group (xor<16 stays in-group)
  lsum += __shfl_xor(lsum, 1, 64);
  lsum += __shfl_xor(lsum, 2, 64);
  lsum += __shfl_xor(lsum, 4, 64);
  lsum += __shfl_xor(lsum, 8, 64);
  float mval = lsum * (1.0f / 144.0f);

  // ---- epilogue: coefficient vectors cached once, full-wave 1KiB stores ----
  const float* sc = cc + 1536;
  float A = sc[0], Bc = sc[1], Cc = sc[2];

  float4 a0v[3], a1v[3], btv[3];
  #pragma unroll
  for (int c = 0; c < 3; ++c) {
    int e = c * 256 + lane * 4;
    a0v[c] = *(const float4*)(cc + e);
    a1v[c] = *(const float4*)(cc + 768 + e);
    btv[c] = *(const float4*)(beta + e);
  }

  int pbase = blockIdx.x * 16 + (tid >> 6) * 4;   // first patch of this wave
  #pragma unroll
  for (int g = 0; g < 4; ++g) {
    float mg   = __shfl(mval, g * 16, 64);        // group g's mean (uniform in group)
    float invg = __frsqrt_rn(fmaf(mg, fmaf(mg, A, 2.0f * Bc), Cc) + EPS_LN);
    size_t ob  = (size_t)(pbase + g) * EMBED + lane * 4;
    #pragma unroll
    for (int c = 0; c < 3; ++c) {
      f32x4_t o;
      o.x = fmaf(fmaf(mg, a0v[c].x, a1v[c].x), invg, btv[c].x);
      o.y = fmaf(fmaf(mg, a0v[c].y, a1v[c].y), invg, btv[c].y);
      o.z = fmaf(fmaf(mg, a0v[c].z, a1v[c].z), invg, btv[c].z);
      o.w = fmaf(fmaf(mg, a0v[c].w, a1v[c].w), invg, btv[c].w);
      // out is write-once, never re-read: nontemporal store keeps L2 clean
      __builtin_nontemporal_store(o, (f32x4_t*)(out + ob + c * 256));
    }
  }
}

extern "C" void kernel_launch(void* const* d_in, const int* in_sizes, int n_in,
                              void* d_out, int out_size, void* d_ws, size_t ws_size,
                              hipStream_t stream) {
  const float* x     = (const float*)d_in[0];
  const float* W     = (const float*)d_in[1];
  const float* b     = (const float*)d_in[2];
  const float* gamma = (const float*)d_in[3];
  const float* beta  = (const float*)d_in[4];
  float* out = (float*)d_out;
  float* cc  = (float*)d_ws;

  fpe_partial<<<32, 768, 0, stream>>>(W, cc);
  fpe_stats<<<1, 768, 0, stream>>>(b, gamma, cc);
  fpe_main<<<TOTAL_PATCH / 16, 256, 0, stream>>>(x, cc, beta, out);
}